// Round 12
// baseline (429.764 us; speedup 1.0000x reference)
//
#include <hip/hip_runtime.h>
#include <hip/hip_bf16.h>

#define N_NODES 50000
#define N_EDGES 800000
#define IN_DIM 64
#define HID_DIM 128
#define OUT_DIM 64
#define NGRP 8
#define NSLC 4                                // feature slices (16 floats = 64B line)
#define NPB 16                                // nodes per agg block
#define ECAP 1024                             // staged edge cap per block
#define NE8 (NGRP * N_NODES)                  // 400000
#define NC8C ((NE8 + 255) / 256)              // 1563 scan chunks (group-major)
#define NCMC ((N_NODES + 255) / 256)          // 196 scan chunks (merged)

// ---- device-global scratch ----
__device__ int g_in_f32;
__device__ int g_is64;
__device__ unsigned g_done;                   // scans last-block ticket (reset each run)
__device__ int g_csr[N_EDGES];                // group-major partitioned CSR
__device__ int g_mcsr[N_EDGES];               // merged node-major CSR
__device__ int g_deg8[NE8];                   // [g][v]
__device__ int g_rowptr8[NE8 + 1];
__device__ int g_cursor8[NE8];
__device__ int g_mrp[N_NODES + 1];
__device__ int g_bsum[NC8C];
__device__ int g_boff[NC8C];
__device__ int g_bsum2[NCMC];
__device__ int g_boff2[NCMC];
__device__ float g_dinv[N_NODES];
__device__ __align__(16) float g_W1f[IN_DIM * HID_DIM];
__device__ __align__(16) float g_W2f[HID_DIM * OUT_DIM];
__device__ __align__(16) float g_b1f[HID_DIM];
__device__ __align__(16) float g_b2f[OUT_DIM];
// g_hs1: aggz out blocked [4][N][16]; then hs2 blocked [4][N][16] (in-place per-row swap in gemm_fused)
__device__ __align__(16) float g_hs1[(size_t)N_NODES * IN_DIM];
// g_agg1: zb blocked [4][N][16] (dinv-scaled z)
__device__ __align__(16) float g_agg1[(size_t)N_NODES * IN_DIM];

__device__ __forceinline__ float loadx(const void* p, int i, int f32) {
    if (f32) return ((const float*)p)[i];
    unsigned int u = ((unsigned int)((const unsigned short*)p)[i]) << 16;
    return __uint_as_float(u);
}

// ---- K1: zero deg8 (grid) + dtype/index detect (block 0) + ticket reset ----
__global__ __launch_bounds__(256) void zerodet_kernel(const unsigned short* __restrict__ zw,
                                                      const unsigned int* __restrict__ ew,
                                                      int NE, int E) {
    int idx = blockIdx.x * 256 + threadIdx.x;
    if (idx < NE) g_deg8[idx] = 0;
    if (blockIdx.x == 0) {
        __shared__ int flags[2];
        int t = threadIdx.x;
        if (t < 2) flags[t] = 0;
        if (t == 0) g_done = 0;
        __syncthreads();
        int hit = 0;
        for (int k = 0; k < 64; k++) {
            int i = 2 * ((t * 64 + k) * 97);
            if (((zw[i] >> 7) & 0xFF) == 0xFF) hit = 1;
        }
        if (hit) atomicOr(&flags[0], 1);
        int nz = 0;
        int step = E / 4096;
        for (int k = 0; k < 4; k++) {
            int i = 1 + 2 * ((t * 4 + k) * step);
            if (ew[i] != 0) nz = 1;
        }
        if (nz) atomicOr(&flags[1], 1);
        __syncthreads();
        if (t == 0) { g_in_f32 = flags[0]; g_is64 = (flags[1] == 0) ? 1 : 0; }
    }
}

// ---- K2: per-group degree count (dst read direct from ei) + weight/bias f32 prep ----
__global__ __launch_bounds__(256) void degprep_kernel(const void* __restrict__ ei,
                                                      const void* __restrict__ W1, const void* __restrict__ b1,
                                                      const void* __restrict__ W2, const void* __restrict__ b2,
                                                      int N, int E) {
    int e = blockIdx.x * 256 + threadIdx.x;
    int f32 = g_in_f32;
    if (e < IN_DIM * HID_DIM) g_W1f[e] = loadx(W1, e, f32);
    if (e < HID_DIM * OUT_DIM) g_W2f[e] = loadx(W2, e, f32);
    if (e < HID_DIM) g_b1f[e] = loadx(b1, e, f32);
    if (e < OUT_DIM) g_b2f[e] = loadx(b2, e, f32);
    if (e < E) {
        int d = g_is64 ? (int)((const long long*)ei)[E + e] : ((const int*)ei)[E + e];
        int g = blockIdx.x & (NGRP - 1);          // round-robin -> XCD-local counters
        atomicAdd(&g_deg8[g * N + d], 1);
    }
}

// ---- K3: chunk-local scans (deg8 g-major; merged + dinv) + LAST-BLOCK block-sum scan ----
__global__ __launch_bounds__(256) void scans_kernel(int N, int NE, int E) {
    __shared__ int sc[256];
    __shared__ int lastflag;
    int t = threadIdx.x;
    int NC8 = (NE + 255) >> 8, NCM = (N + 255) >> 8;
    for (int vb = blockIdx.x; vb < NC8; vb += gridDim.x) {
        int idx = (vb << 8) + t;
        int d = (idx < NE) ? g_deg8[idx] : 0;
        sc[t] = d;
        __syncthreads();
        for (int off = 1; off < 256; off <<= 1) {
            int v = (t >= off) ? sc[t - off] : 0;
            __syncthreads();
            sc[t] += v;
            __syncthreads();
        }
        if (idx < NE) g_rowptr8[idx] = sc[t] - d;
        if (t == 255) g_bsum[vb] = sc[255];
        __syncthreads();
    }
    for (int vb = blockIdx.x; vb < NCM; vb += gridDim.x) {
        int idx = (vb << 8) + t;
        int d = 0;
        if (idx < N) {
#pragma unroll
            for (int g = 0; g < NGRP; g++) d += g_deg8[g * N + idx];
            g_dinv[idx] = rsqrtf((float)d + 1.0f);  // +1 = self loop
        }
        sc[t] = d;
        __syncthreads();
        for (int off = 1; off < 256; off <<= 1) {
            int v = (t >= off) ? sc[t - off] : 0;
            __syncthreads();
            sc[t] += v;
            __syncthreads();
        }
        if (idx < N) g_mrp[idx] = sc[t] - d;
        if (t == 255) g_bsum2[vb] = sc[255];
        __syncthreads();
    }
    // ---- last finishing block scans the block sums (no spin; deadlock-free) ----
    __threadfence();
    __syncthreads();
    if (t == 0) {
        unsigned tk = atomicAdd(&g_done, 1u);
        lastflag = (tk == gridDim.x - 1);
    }
    __syncthreads();
    if (!lastflag) return;
    __threadfence();  // acquire: see all blocks' bsum writes
    {   // g-major bsum: 8 values/thread serial + one 256-scan
        int loc[8];
        int s = 0;
#pragma unroll
        for (int j = 0; j < 8; j++) {
            int i = t * 8 + j;
            int v = (i < NC8) ? g_bsum[i] : 0;
            loc[j] = s;
            s += v;
        }
        sc[t] = s;
        __syncthreads();
        for (int off = 1; off < 256; off <<= 1) {
            int v = (t >= off) ? sc[t - off] : 0;
            __syncthreads();
            sc[t] += v;
            __syncthreads();
        }
        int excl = sc[t] - s;
#pragma unroll
        for (int j = 0; j < 8; j++) {
            int i = t * 8 + j;
            if (i < NC8) g_boff[i] = excl + loc[j];
        }
        __syncthreads();
    }
    {   // merged bsum2 (<=256)
        int v = (t < NCM) ? g_bsum2[t] : 0;
        sc[t] = v;
        __syncthreads();
        for (int off = 1; off < 256; off <<= 1) {
            int u = (t >= off) ? sc[t - off] : 0;
            __syncthreads();
            sc[t] += u;
            __syncthreads();
        }
        if (t < NCM) g_boff2[t] = sc[t] - v;
    }
    if (t == 0) { g_rowptr8[NE] = E; g_mrp[N] = E; }
}

// ---- K4: add block offsets, finalize rowptr8+cursor8 and mrp ----
__global__ __launch_bounds__(256) void addoffs_kernel(int N, int NE) {
    int idx = blockIdx.x * 256 + threadIdx.x;
    if (idx < NE) {
        int base = g_rowptr8[idx] + g_boff[blockIdx.x];
        g_rowptr8[idx] = base;
        g_cursor8[idx] = base;
    }
    if ((int)blockIdx.x < (N + 255) / 256 && idx < (blockIdx.x + 1) * 256) {
        int i2 = idx;
        if (i2 < N) g_mrp[i2] += g_boff2[blockIdx.x];
    }
}

// ---- K5: scatter edges into group-partitioned CSR (src/dst direct from ei) ----
__global__ __launch_bounds__(256) void scatter_kernel(const void* __restrict__ ei, int N, int E) {
    int e = blockIdx.x * 256 + threadIdx.x;
    if (e < E) {
        int s, d;
        if (g_is64) { const long long* p = (const long long*)ei; s = (int)p[e]; d = (int)p[E + e]; }
        else        { const int* p = (const int*)ei; s = p[e]; d = p[E + e]; }
        int g = blockIdx.x & (NGRP - 1);
        int pos = atomicAdd(&g_cursor8[g * N + d], 1);
        g_csr[pos] = s;
    }
}

// ---- K6: merge group CSR -> node-major mcsr (wave/node) + zprep blocked ----
__global__ __launch_bounds__(256) void mergezp_kernel(const void* __restrict__ z, int N) {
    int gid = blockIdx.x * 256 + threadIdx.x;
    int wid = gid >> 6;
    int lane = threadIdx.x & 63;
    if (wid < N) {
        int mybeg = 0, mycnt = 0;
        if (lane < NGRP) {
            mybeg = g_rowptr8[lane * N + wid];
            mycnt = g_rowptr8[lane * N + wid + 1] - mybeg;
        }
        int incl = mycnt;
#pragma unroll
        for (int off = 1; off < NGRP; off <<= 1) {
            int v = __shfl_up(incl, off, 64);
            if (lane >= off) incl += v;
        }
        int myoff = incl - mycnt;
        int go[NGRP], gb[NGRP];
#pragma unroll
        for (int k = 0; k < NGRP; k++) {
            go[k] = __shfl(myoff, k, 64);
            gb[k] = __shfl(mybeg, k, 64);
        }
        int total = __shfl(incl, NGRP - 1, 64);
        int base = g_mrp[wid];
        for (int i = lane; i < total; i += 64) {
            int g = 0;
#pragma unroll
            for (int k = 1; k < NGRP; k++) g += (i >= go[k]);
            g_mcsr[base + i] = g_csr[gb[g] + i - go[g]];
        }
    }
    if (gid < N * IN_DIM) {
        int node = gid >> 6, c = gid & 63;
        int s = c >> 4, off = c & 15;
        g_agg1[(size_t)s * (N * 16) + node * 16 + off] = loadx(z, gid, g_in_f32) * g_dinv[node];
    }
}

// ---- K7/K9: block-staged sliced aggregation (16 nodes x 1 slice per block) ----
// slice pinned via blockIdx&3 -> per-XCD 3.2MB table stays L2-resident.
template <int LAYER2>
__global__ __launch_bounds__(256) void aggslc_kernel(void* __restrict__ outp, int N) {
    __shared__ int rp[NPB + 1];
    __shared__ int eidx[ECAP];
    int s = blockIdx.x & (NSLC - 1);
    int n0 = (blockIdx.x >> 2) * NPB;
    int t = threadIdx.x;
    if (t <= NPB) {
        int idx = n0 + t;
        rp[t] = g_mrp[idx <= N ? idx : N];
    }
    __syncthreads();
    int base = rp[0];
    int range = rp[NPB] - base;
    bool staged = (range <= ECAP);
    if (staged) {
        for (int i = t; i < range; i += 256) eidx[i] = g_mcsr[base + i];
    }
    __syncthreads();
    const float* tab = (LAYER2 ? g_hs1 : g_agg1) + (size_t)s * ((size_t)N * 16);
    int lane = t & 63;
    int w4 = (t >> 6) * 4;
    int col = lane & 15, eslot = lane >> 4;
    float res[4];
#pragma unroll
    for (int k = 0; k < 4; k++) {
        int jb = rp[w4 + k] - base + eslot;
        int je = rp[w4 + k + 1] - base;
        float a0 = 0.f, a1 = 0.f, a2 = 0.f, a3 = 0.f;
        int j = jb;
        if (staged) {
            for (; j + 12 < je; j += 16) {
                int i0 = eidx[j], i1 = eidx[j + 4], i2 = eidx[j + 8], i3 = eidx[j + 12];
                a0 += tab[i0 * 16 + col];
                a1 += tab[i1 * 16 + col];
                a2 += tab[i2 * 16 + col];
                a3 += tab[i3 * 16 + col];
            }
            for (; j < je; j += 4) a0 += tab[eidx[j] * 16 + col];
        } else {
            for (; j < je; j += 4) a0 += tab[g_mcsr[base + j] * 16 + col];
        }
        float a = (a0 + a1) + (a2 + a3);
        a += __shfl_xor(a, 16, 64);
        a += __shfl_xor(a, 32, 64);
        res[k] = a;
    }
    if (lane < 16) {
#pragma unroll
        for (int k = 0; k < 4; k++) {
            int nk = n0 + w4 + k;
            if (nk < N) {
                float v = (res[k] + tab[(size_t)nk * 16 + col]) * g_dinv[nk];
                if (LAYER2) {
                    v += g_b2f[s * 16 + col];
                    int oc = nk * 64 + s * 16 + col;
                    if (g_in_f32) ((float*)outp)[oc] = v;
                    else ((__hip_bfloat16*)outp)[oc] = __float2bfloat16(v);
                } else {
                    g_hs1[(size_t)s * ((size_t)N * 16) + nk * 16 + col] = v;
                }
            }
        }
    }
}

// ---- K8: FUSED MLP per 32-row block: hs2 = (relu(aggz@W1+b1))@W2 * dinv ----
// Single UNION LDS buffer [32][132] (16.9 KB): holds aggz^T (k<64) during gemm1,
// then h (k<128) for gemm2 — gemm1 accs live in registers across the swap.
// Stride 132 (528B rows, 16B-aligned) keeps all accesses conflict-free.
__global__ __launch_bounds__(256, 6) void gemm_fused_kernel(int N) {
    __shared__ __align__(16) float B[32 * 132];   // 16896 B
    int t = threadIdx.x;
    int row0 = blockIdx.x * 32;
    // stage aggz (blocked [4][N][16]) row-major into B: float4 per thread x2
#pragma unroll
    for (int s = 0; s < 2; s++) {
        int i = t + s * 256;              // 512 float4s = 32 rows x 16
        int r = i >> 4, k4 = i & 15;
        int row = row0 + r;
        int g = k4 >> 2, off = (k4 & 3) * 4;
        float4 v = make_float4(0.f, 0.f, 0.f, 0.f);
        if (row < N) v = *(const float4*)&g_hs1[(size_t)g * (N * 16) + row * 16 + off];
        *(float4*)&B[r * 132 + k4 * 4] = v;
    }
    __syncthreads();
    // gemm1: 32 colgroups x 8 rowgroups, 4x4 micro-tile -> registers
    int cg1 = t & 31, rg1 = t >> 5;
    int c1 = cg1 * 4, r1 = rg1 * 4;
    float acc1[4][4] = {};
#pragma unroll 8
    for (int k = 0; k < IN_DIM; k++) {
        float b[4];
        *(float4*)b = *(const float4*)&g_W1f[k * HID_DIM + c1];
        float a[4];
        a[0] = B[(r1 + 0) * 132 + k];
        a[1] = B[(r1 + 1) * 132 + k];
        a[2] = B[(r1 + 2) * 132 + k];
        a[3] = B[(r1 + 3) * 132 + k];
#pragma unroll
        for (int i = 0; i < 4; i++)
#pragma unroll
            for (int j = 0; j < 4; j++) acc1[i][j] = fmaf(a[i], b[j], acc1[i][j]);
    }
    __syncthreads();   // all Zs reads complete before h overwrites the buffer
    {
        float4 bias = *(const float4*)&g_b1f[c1];
#pragma unroll
        for (int i = 0; i < 4; i++) {
            float4 v;
            v.x = fmaxf(acc1[i][0] + bias.x, 0.f);
            v.y = fmaxf(acc1[i][1] + bias.y, 0.f);
            v.z = fmaxf(acc1[i][2] + bias.z, 0.f);
            v.w = fmaxf(acc1[i][3] + bias.w, 0.f);
            *(float4*)&B[(r1 + i) * 132 + c1] = v;   // conflict-free b128
        }
    }
    __syncthreads();
    // gemm2: 16 colgroups x 16 rowgroups, 2x4 micro-tile; K=128 via float4 chunks of B
    {
        int cg = t & 15, rg = t >> 4;
        int c0 = cg * 4, r0 = rg * 2;
        float acc[2][4] = {};
#pragma unroll 4
        for (int k4 = 0; k4 < 32; k4++) {
            float a0v[4], a1v[4];
            *(float4*)a0v = *(const float4*)&B[(r0 + 0) * 132 + k4 * 4];
            *(float4*)a1v = *(const float4*)&B[(r0 + 1) * 132 + k4 * 4];
#pragma unroll
            for (int jj = 0; jj < 4; jj++) {
                float b[4];
                *(float4*)b = *(const float4*)&g_W2f[(k4 * 4 + jj) * OUT_DIM + c0];
#pragma unroll
                for (int j = 0; j < 4; j++) {
                    acc[0][j] = fmaf(a0v[jj], b[j], acc[0][j]);
                    acc[1][j] = fmaf(a1v[jj], b[j], acc[1][j]);
                }
            }
        }
        int g = cg >> 2, off = (cg & 3) * 4;  // blocked output [4][N][16]
#pragma unroll
        for (int i = 0; i < 2; i++) {
            int row = row0 + r0 + i;
            if (row < N) {
                float dn = g_dinv[row];
                float4 v;
                v.x = acc[i][0] * dn;
                v.y = acc[i][1] * dn;
                v.z = acc[i][2] * dn;
                v.w = acc[i][3] * dn;
                *(float4*)&g_hs1[(size_t)g * (N * 16) + row * 16 + off] = v;
            }
        }
    }
}

extern "C" void kernel_launch(void* const* d_in, const int* in_sizes, int n_in,
                              void* d_out, int out_size, void* d_ws, size_t ws_size,
                              hipStream_t stream) {
    const void* z  = d_in[0];
    const void* ei = d_in[1];
    const void* W1 = d_in[2];
    const void* b1 = d_in[3];
    const void* W2 = d_in[4];
    const void* b2 = d_in[5];

    const int N = in_sizes[0] / IN_DIM;  // 50000
    const int E = in_sizes[1] / 2;       // 800000
    const int NE = NGRP * N;             // 400000
    const int NC8 = (NE + 255) / 256;    // 1563
    const int aggblocks = NSLC * ((N + NPB - 1) / NPB);  // 12500

    zerodet_kernel<<<NC8, 256, 0, stream>>>((const unsigned short*)z, (const unsigned int*)ei, NE, E);
    degprep_kernel<<<(E + 255) / 256, 256, 0, stream>>>(ei, W1, b1, W2, b2, N, E);
    scans_kernel<<<NC8, 256, 0, stream>>>(N, NE, E);
    addoffs_kernel<<<NC8, 256, 0, stream>>>(N, NE);
    scatter_kernel<<<(E + 255) / 256, 256, 0, stream>>>(ei, N, E);
    mergezp_kernel<<<(N * 64 + 255) / 256, 256, 0, stream>>>(z, N);

    aggslc_kernel<0><<<aggblocks, 256, 0, stream>>>(d_out, N);
    gemm_fused_kernel<<<(N + 31) / 32, 256, 0, stream>>>(N);
    aggslc_kernel<1><<<aggblocks, 256, 0, stream>>>(d_out, N);
}

// Round 13
// 319.809 us; speedup vs baseline: 1.3438x; 1.3438x over previous
//
#include <hip/hip_runtime.h>
#include <hip/hip_bf16.h>

#define N_NODES 50000
#define N_EDGES 800000
#define IN_DIM 64
#define HID_DIM 128
#define OUT_DIM 64
#define NGRP 8
#define NSLC 4                                // feature slices (16 floats = 64B line)
#define NPB 32                                // nodes per agg block
#define ECAP 2048                             // staged edge cap per block
#define NE8 (NGRP * N_NODES)                  // 400000
#define NC8C ((NE8 + 255) / 256)              // 1563 scan chunks (group-major)
#define NCMC ((N_NODES + 255) / 256)          // 196 scan chunks (merged)

// ---- device-global scratch ----
__device__ int g_in_f32;
__device__ int g_is64;
__device__ int g_csr[N_EDGES];                // group-major partitioned CSR
__device__ int g_mcsr[N_EDGES];               // merged node-major CSR
__device__ int g_deg8[NE8];                   // [g][v]
__device__ int g_rowptr8[NE8 + 1];
__device__ int g_cursor8[NE8];
__device__ int g_mrp[N_NODES + 1];
__device__ int g_bsum[NC8C];
__device__ int g_bsum2[NCMC];
__device__ float g_dinv[N_NODES];
__device__ __align__(16) float g_W1f[IN_DIM * HID_DIM];
__device__ __align__(16) float g_W2f[HID_DIM * OUT_DIM];
__device__ __align__(16) float g_b1f[HID_DIM];
__device__ __align__(16) float g_b2f[OUT_DIM];
// g_hs1: aggz out blocked [4][N][16]; then hs2 blocked [4][N][16] (in-place per-row swap in gemm_fused)
__device__ __align__(16) float g_hs1[(size_t)N_NODES * IN_DIM];
// g_agg1: zb blocked [4][N][16] (dinv-scaled z)
__device__ __align__(16) float g_agg1[(size_t)N_NODES * IN_DIM];

__device__ __forceinline__ float loadx(const void* p, int i, int f32) {
    if (f32) return ((const float*)p)[i];
    unsigned int u = ((unsigned int)((const unsigned short*)p)[i]) << 16;
    return __uint_as_float(u);
}

// ---- K1: zero deg8 (grid) + dtype/index detect (block 0) ----
__global__ __launch_bounds__(256) void zerodet_kernel(const unsigned short* __restrict__ zw,
                                                      const unsigned int* __restrict__ ew,
                                                      int NE, int E) {
    int idx = blockIdx.x * 256 + threadIdx.x;
    if (idx < NE) g_deg8[idx] = 0;
    if (blockIdx.x == 0) {
        __shared__ int flags[2];
        int t = threadIdx.x;
        if (t < 2) flags[t] = 0;
        __syncthreads();
        int hit = 0;
        for (int k = 0; k < 64; k++) {
            int i = 2 * ((t * 64 + k) * 97);
            if (((zw[i] >> 7) & 0xFF) == 0xFF) hit = 1;
        }
        if (hit) atomicOr(&flags[0], 1);
        int nz = 0;
        int step = E / 4096;
        for (int k = 0; k < 4; k++) {
            int i = 1 + 2 * ((t * 4 + k) * step);
            if (ew[i] != 0) nz = 1;
        }
        if (nz) atomicOr(&flags[1], 1);
        __syncthreads();
        if (t == 0) { g_in_f32 = flags[0]; g_is64 = (flags[1] == 0) ? 1 : 0; }
    }
}

// ---- K2: per-group degree count (dst read direct from ei) + weight/bias f32 prep ----
__global__ __launch_bounds__(256) void degprep_kernel(const void* __restrict__ ei,
                                                      const void* __restrict__ W1, const void* __restrict__ b1,
                                                      const void* __restrict__ W2, const void* __restrict__ b2,
                                                      int N, int E) {
    int e = blockIdx.x * 256 + threadIdx.x;
    int f32 = g_in_f32;
    if (e < IN_DIM * HID_DIM) g_W1f[e] = loadx(W1, e, f32);
    if (e < HID_DIM * OUT_DIM) g_W2f[e] = loadx(W2, e, f32);
    if (e < HID_DIM) g_b1f[e] = loadx(b1, e, f32);
    if (e < OUT_DIM) g_b2f[e] = loadx(b2, e, f32);
    if (e < E) {
        int d = g_is64 ? (int)((const long long*)ei)[E + e] : ((const int*)ei)[E + e];
        int g = blockIdx.x & (NGRP - 1);          // round-robin -> XCD-local counters
        atomicAdd(&g_deg8[g * N + d], 1);
    }
}

// ---- K3: chunk-local scans ONLY (no fences, no cross-block ordering) ----
__global__ __launch_bounds__(256) void scans_kernel(int N, int NE) {
    __shared__ int sc[256];
    int t = threadIdx.x;
    int NC8 = (NE + 255) >> 8, NCM = (N + 255) >> 8;
    for (int vb = blockIdx.x; vb < NC8; vb += gridDim.x) {
        int idx = (vb << 8) + t;
        int d = (idx < NE) ? g_deg8[idx] : 0;
        sc[t] = d;
        __syncthreads();
        for (int off = 1; off < 256; off <<= 1) {
            int v = (t >= off) ? sc[t - off] : 0;
            __syncthreads();
            sc[t] += v;
            __syncthreads();
        }
        if (idx < NE) g_rowptr8[idx] = sc[t] - d;  // local exclusive prefix
        if (t == 255) g_bsum[vb] = sc[255];
        __syncthreads();
    }
    for (int vb = blockIdx.x; vb < NCM; vb += gridDim.x) {
        int idx = (vb << 8) + t;
        int d = 0;
        if (idx < N) {
#pragma unroll
            for (int g = 0; g < NGRP; g++) d += g_deg8[g * N + idx];
            g_dinv[idx] = rsqrtf((float)d + 1.0f);  // +1 = self loop
        }
        sc[t] = d;
        __syncthreads();
        for (int off = 1; off < 256; off <<= 1) {
            int v = (t >= off) ? sc[t - off] : 0;
            __syncthreads();
            sc[t] += v;
            __syncthreads();
        }
        if (idx < N) g_mrp[idx] = sc[t] - d;
        if (t == 255) g_bsum2[vb] = sc[255];
        __syncthreads();
    }
}

// ---- K4: per-block prefix over bsum (L2-hot) + add offsets; finalize rowptr8/cursor8/mrp ----
// reads of g_bsum/g_bsum2 are ordered by the kernel boundary -> no fences needed
__global__ __launch_bounds__(256) void addoffs_kernel(int N, int NE, int E) {
    __shared__ int sc[256];
    int t = threadIdx.x;
    int vb = blockIdx.x;
    int NCM = (N + 255) >> 8;
    int ps = 0;
    for (int i = t; i < vb; i += 256) ps += g_bsum[i];
    sc[t] = ps;
    __syncthreads();
    for (int off = 128; off > 0; off >>= 1) {
        if (t < off) sc[t] += sc[t + off];
        __syncthreads();
    }
    int prefix = sc[0];
    __syncthreads();
    int idx = vb * 256 + t;
    if (idx < NE) {
        int base = g_rowptr8[idx] + prefix;
        g_rowptr8[idx] = base;
        g_cursor8[idx] = base;
    }
    if (vb < NCM) {
        int ps2 = 0;
        for (int i = t; i < vb; i += 256) ps2 += g_bsum2[i];
        sc[t] = ps2;
        __syncthreads();
        for (int off = 128; off > 0; off >>= 1) {
            if (t < off) sc[t] += sc[t + off];
            __syncthreads();
        }
        int prefix2 = sc[0];
        if (idx < N) g_mrp[idx] += prefix2;
    }
    if (vb == 0 && t == 0) { g_rowptr8[NE] = E; g_mrp[N] = E; }
}

// ---- K5: scatter edges into group-partitioned CSR (src/dst direct from ei) ----
__global__ __launch_bounds__(256) void scatter_kernel(const void* __restrict__ ei, int N, int E) {
    int e = blockIdx.x * 256 + threadIdx.x;
    if (e < E) {
        int s, d;
        if (g_is64) { const long long* p = (const long long*)ei; s = (int)p[e]; d = (int)p[E + e]; }
        else        { const int* p = (const int*)ei; s = p[e]; d = p[E + e]; }
        int g = blockIdx.x & (NGRP - 1);
        int pos = atomicAdd(&g_cursor8[g * N + d], 1);
        g_csr[pos] = s;
    }
}

// ---- K6: merge group CSR -> node-major mcsr (wave/node) + zprep blocked ----
__global__ __launch_bounds__(256) void mergezp_kernel(const void* __restrict__ z, int N) {
    int gid = blockIdx.x * 256 + threadIdx.x;
    int wid = gid >> 6;
    int lane = threadIdx.x & 63;
    if (wid < N) {
        int mybeg = 0, mycnt = 0;
        if (lane < NGRP) {
            mybeg = g_rowptr8[lane * N + wid];
            mycnt = g_rowptr8[lane * N + wid + 1] - mybeg;
        }
        int incl = mycnt;
#pragma unroll
        for (int off = 1; off < NGRP; off <<= 1) {
            int v = __shfl_up(incl, off, 64);
            if (lane >= off) incl += v;
        }
        int myoff = incl - mycnt;
        int go[NGRP], gb[NGRP];
#pragma unroll
        for (int k = 0; k < NGRP; k++) {
            go[k] = __shfl(myoff, k, 64);
            gb[k] = __shfl(mybeg, k, 64);
        }
        int total = __shfl(incl, NGRP - 1, 64);
        int base = g_mrp[wid];
        for (int i = lane; i < total; i += 64) {
            int g = 0;
#pragma unroll
            for (int k = 1; k < NGRP; k++) g += (i >= go[k]);
            g_mcsr[base + i] = g_csr[gb[g] + i - go[g]];
        }
    }
    if (gid < N * IN_DIM) {
        int node = gid >> 6, c = gid & 63;
        int s = c >> 4, off = c & 15;
        g_agg1[(size_t)s * (N * 16) + node * 16 + off] = loadx(z, gid, g_in_f32) * g_dinv[node];
    }
}

// ---- K7/K9: block-staged sliced aggregation (32 nodes x 1 slice per block) ----
// slice pinned via blockIdx&3 -> per-XCD 3.2MB table stays L2-resident.
template <int LAYER2>
__global__ __launch_bounds__(256) void aggslc_kernel(void* __restrict__ outp, int N) {
    __shared__ int rp[NPB + 1];
    __shared__ int eidx[ECAP];
    int s = blockIdx.x & (NSLC - 1);
    int n0 = (blockIdx.x >> 2) * NPB;
    int t = threadIdx.x;
    if (t <= NPB) {
        int idx = n0 + t;
        rp[t] = g_mrp[idx <= N ? idx : N];
    }
    __syncthreads();
    int base = rp[0];
    int range = rp[NPB] - base;
    bool staged = (range <= ECAP);
    if (staged) {
        for (int i = t; i < range; i += 256) eidx[i] = g_mcsr[base + i];
    }
    __syncthreads();
    const float* tab = (LAYER2 ? g_hs1 : g_agg1) + (size_t)s * ((size_t)N * 16);
    int lane = t & 63;
    int w8 = (t >> 6) * 8;
    int col = lane & 15, eslot = lane >> 4;
    float res[8];
#pragma unroll
    for (int k = 0; k < 8; k++) {
        int jb = rp[w8 + k] - base + eslot;
        int je = rp[w8 + k + 1] - base;
        float a0 = 0.f, a1 = 0.f, a2 = 0.f, a3 = 0.f;
        int j = jb;
        if (staged) {
            for (; j + 12 < je; j += 16) {
                int i0 = eidx[j], i1 = eidx[j + 4], i2 = eidx[j + 8], i3 = eidx[j + 12];
                a0 += tab[i0 * 16 + col];
                a1 += tab[i1 * 16 + col];
                a2 += tab[i2 * 16 + col];
                a3 += tab[i3 * 16 + col];
            }
            for (; j < je; j += 4) a0 += tab[eidx[j] * 16 + col];
        } else {
            for (; j < je; j += 4) a0 += tab[g_mcsr[base + j] * 16 + col];
        }
        float a = (a0 + a1) + (a2 + a3);
        a += __shfl_xor(a, 16, 64);
        a += __shfl_xor(a, 32, 64);
        res[k] = a;
    }
    if (lane < 16) {
#pragma unroll
        for (int k = 0; k < 8; k++) {
            int nk = n0 + w8 + k;
            if (nk < N) {
                float v = (res[k] + tab[(size_t)nk * 16 + col]) * g_dinv[nk];
                if (LAYER2) {
                    v += g_b2f[s * 16 + col];
                    int oc = nk * 64 + s * 16 + col;
                    if (g_in_f32) ((float*)outp)[oc] = v;
                    else ((__hip_bfloat16*)outp)[oc] = __float2bfloat16(v);
                } else {
                    g_hs1[(size_t)s * ((size_t)N * 16) + nk * 16 + col] = v;
                }
            }
        }
    }
}

// ---- K8: FUSED MLP per 32-row block: hs2 = (relu(aggz@W1+b1))@W2 * dinv ----
// Single UNION LDS buffer [32][132] (16.9 KB): holds aggz^T (k<64) during gemm1,
// then h (k<128) for gemm2 — gemm1 accs live in registers across the swap.
// Stride 132 (528B rows, 16B-aligned) keeps all accesses conflict-free.
__global__ __launch_bounds__(256) void gemm_fused_kernel(int N) {
    __shared__ __align__(16) float B[32 * 132];   // 16896 B
    int t = threadIdx.x;
    int row0 = blockIdx.x * 32;
    // stage aggz (blocked [4][N][16]) row-major into B: float4 per thread x2
#pragma unroll
    for (int s = 0; s < 2; s++) {
        int i = t + s * 256;              // 512 float4s = 32 rows x 16
        int r = i >> 4, k4 = i & 15;
        int row = row0 + r;
        int g = k4 >> 2, off = (k4 & 3) * 4;
        float4 v = make_float4(0.f, 0.f, 0.f, 0.f);
        if (row < N) v = *(const float4*)&g_hs1[(size_t)g * (N * 16) + row * 16 + off];
        *(float4*)&B[r * 132 + k4 * 4] = v;
    }
    __syncthreads();
    // gemm1: 32 colgroups x 8 rowgroups, 4x4 micro-tile -> registers
    int cg1 = t & 31, rg1 = t >> 5;
    int c1 = cg1 * 4, r1 = rg1 * 4;
    float acc1[4][4] = {};
#pragma unroll 8
    for (int k = 0; k < IN_DIM; k++) {
        float b[4];
        *(float4*)b = *(const float4*)&g_W1f[k * HID_DIM + c1];
        float a[4];
        a[0] = B[(r1 + 0) * 132 + k];
        a[1] = B[(r1 + 1) * 132 + k];
        a[2] = B[(r1 + 2) * 132 + k];
        a[3] = B[(r1 + 3) * 132 + k];
#pragma unroll
        for (int i = 0; i < 4; i++)
#pragma unroll
            for (int j = 0; j < 4; j++) acc1[i][j] = fmaf(a[i], b[j], acc1[i][j]);
    }
    __syncthreads();   // all Zs reads complete before h overwrites the buffer
    {
        float4 bias = *(const float4*)&g_b1f[c1];
#pragma unroll
        for (int i = 0; i < 4; i++) {
            float4 v;
            v.x = fmaxf(acc1[i][0] + bias.x, 0.f);
            v.y = fmaxf(acc1[i][1] + bias.y, 0.f);
            v.z = fmaxf(acc1[i][2] + bias.z, 0.f);
            v.w = fmaxf(acc1[i][3] + bias.w, 0.f);
            *(float4*)&B[(r1 + i) * 132 + c1] = v;   // conflict-free b128
        }
    }
    __syncthreads();
    // gemm2: 16 colgroups x 16 rowgroups, 2x4 micro-tile; K=128 via float4 chunks of B
    {
        int cg = t & 15, rg = t >> 4;
        int c0 = cg * 4, r0 = rg * 2;
        float acc[2][4] = {};
#pragma unroll 4
        for (int k4 = 0; k4 < 32; k4++) {
            float a0v[4], a1v[4];
            *(float4*)a0v = *(const float4*)&B[(r0 + 0) * 132 + k4 * 4];
            *(float4*)a1v = *(const float4*)&B[(r0 + 1) * 132 + k4 * 4];
#pragma unroll
            for (int jj = 0; jj < 4; jj++) {
                float b[4];
                *(float4*)b = *(const float4*)&g_W2f[(k4 * 4 + jj) * OUT_DIM + c0];
#pragma unroll
                for (int j = 0; j < 4; j++) {
                    acc[0][j] = fmaf(a0v[jj], b[j], acc[0][j]);
                    acc[1][j] = fmaf(a1v[jj], b[j], acc[1][j]);
                }
            }
        }
        int g = cg >> 2, off = (cg & 3) * 4;  // blocked output [4][N][16]
#pragma unroll
        for (int i = 0; i < 2; i++) {
            int row = row0 + r0 + i;
            if (row < N) {
                float dn = g_dinv[row];
                float4 v;
                v.x = acc[i][0] * dn;
                v.y = acc[i][1] * dn;
                v.z = acc[i][2] * dn;
                v.w = acc[i][3] * dn;
                *(float4*)&g_hs1[(size_t)g * (N * 16) + row * 16 + off] = v;
            }
        }
    }
}

extern "C" void kernel_launch(void* const* d_in, const int* in_sizes, int n_in,
                              void* d_out, int out_size, void* d_ws, size_t ws_size,
                              hipStream_t stream) {
    const void* z  = d_in[0];
    const void* ei = d_in[1];
    const void* W1 = d_in[2];
    const void* b1 = d_in[3];
    const void* W2 = d_in[4];
    const void* b2 = d_in[5];

    const int N = in_sizes[0] / IN_DIM;  // 50000
    const int E = in_sizes[1] / 2;       // 800000
    const int NE = NGRP * N;             // 400000
    const int NC8 = (NE + 255) / 256;    // 1563
    const int aggblocks = NSLC * ((N + NPB - 1) / NPB);  // 6252

    zerodet_kernel<<<NC8, 256, 0, stream>>>((const unsigned short*)z, (const unsigned int*)ei, NE, E);
    degprep_kernel<<<(E + 255) / 256, 256, 0, stream>>>(ei, W1, b1, W2, b2, N, E);
    scans_kernel<<<NC8, 256, 0, stream>>>(N, NE);
    addoffs_kernel<<<NC8, 256, 0, stream>>>(N, NE, E);
    scatter_kernel<<<(E + 255) / 256, 256, 0, stream>>>(ei, N, E);
    mergezp_kernel<<<(N * 64 + 255) / 256, 256, 0, stream>>>(z, N);

    aggslc_kernel<0><<<aggblocks, 256, 0, stream>>>(d_out, N);
    gemm_fused_kernel<<<(N + 31) / 32, 256, 0, stream>>>(N);
    aggslc_kernel<1><<<aggblocks, 256, 0, stream>>>(d_out, N);
}

// Round 14
// 301.316 us; speedup vs baseline: 1.4263x; 1.0614x over previous
//
#include <hip/hip_runtime.h>
#include <hip/hip_bf16.h>

#define N_NODES 50000
#define N_EDGES 800000
#define IN_DIM 64
#define HID_DIM 128
#define OUT_DIM 64
#define NGRP 8
#define NSLC 4                                // feature slices (16 floats = 64B line)
#define NPB 32                                // nodes per agg block
#define ECAP 2048                             // staged edge cap per block
#define NE8 (NGRP * N_NODES)                  // 400000
#define NC8C ((NE8 + 255) / 256)              // 1563 scan chunks (group-major)
#define NCMC ((N_NODES + 255) / 256)          // 196 scan chunks (merged)

// ---- device-global scratch ----
__device__ int g_in_f32;
__device__ int g_is64;
__device__ int g_csr[N_EDGES];                // group-major partitioned CSR
__device__ int g_mcsr[N_EDGES];               // merged node-major CSR
__device__ int g_deg8[NE8];                   // [g][v]
__device__ int g_rowptr8[NE8 + 1];
__device__ int g_cursor8[NE8];
__device__ int g_mrp[N_NODES + 1];
__device__ int g_bsum[NC8C];
__device__ int g_bsum2[NCMC];
__device__ float g_dinv[N_NODES];
__device__ __align__(16) float g_W1f[IN_DIM * HID_DIM];
__device__ __align__(16) float g_W2f[HID_DIM * OUT_DIM];
__device__ __align__(16) float g_b1f[HID_DIM];
__device__ __align__(16) float g_b2f[OUT_DIM];
// g_hs1: aggz out blocked [4][N][16]; then hs2 blocked [4][N][16] (in-place per-row swap in gemm_fused)
__device__ __align__(16) float g_hs1[(size_t)N_NODES * IN_DIM];
// g_agg1: zb blocked [4][N][16] (dinv-scaled z)
__device__ __align__(16) float g_agg1[(size_t)N_NODES * IN_DIM];

__device__ __forceinline__ float loadx(const void* p, int i, int f32) {
    if (f32) return ((const float*)p)[i];
    unsigned int u = ((unsigned int)((const unsigned short*)p)[i]) << 16;
    return __uint_as_float(u);
}

// ---- K1: zero deg8 (grid) + dtype/index detect (block 0) ----
__global__ __launch_bounds__(256) void zerodet_kernel(const unsigned short* __restrict__ zw,
                                                      const unsigned int* __restrict__ ew,
                                                      int NE, int E) {
    int idx = blockIdx.x * 256 + threadIdx.x;
    if (idx < NE) g_deg8[idx] = 0;
    if (blockIdx.x == 0) {
        __shared__ int flags[2];
        int t = threadIdx.x;
        if (t < 2) flags[t] = 0;
        __syncthreads();
        int hit = 0;
        for (int k = 0; k < 64; k++) {
            int i = 2 * ((t * 64 + k) * 97);
            if (((zw[i] >> 7) & 0xFF) == 0xFF) hit = 1;
        }
        if (hit) atomicOr(&flags[0], 1);
        int nz = 0;
        int step = E / 4096;
        for (int k = 0; k < 4; k++) {
            int i = 1 + 2 * ((t * 4 + k) * step);
            if (ew[i] != 0) nz = 1;
        }
        if (nz) atomicOr(&flags[1], 1);
        __syncthreads();
        if (t == 0) { g_in_f32 = flags[0]; g_is64 = (flags[1] == 0) ? 1 : 0; }
    }
}

// ---- K2: per-group degree count (dst read direct from ei) + weight/bias f32 prep ----
__global__ __launch_bounds__(256) void degprep_kernel(const void* __restrict__ ei,
                                                      const void* __restrict__ W1, const void* __restrict__ b1,
                                                      const void* __restrict__ W2, const void* __restrict__ b2,
                                                      int N, int E) {
    int e = blockIdx.x * 256 + threadIdx.x;
    int f32 = g_in_f32;
    if (e < IN_DIM * HID_DIM) g_W1f[e] = loadx(W1, e, f32);
    if (e < HID_DIM * OUT_DIM) g_W2f[e] = loadx(W2, e, f32);
    if (e < HID_DIM) g_b1f[e] = loadx(b1, e, f32);
    if (e < OUT_DIM) g_b2f[e] = loadx(b2, e, f32);
    if (e < E) {
        int d = g_is64 ? (int)((const long long*)ei)[E + e] : ((const int*)ei)[E + e];
        int g = blockIdx.x & (NGRP - 1);          // round-robin -> XCD-local counters
        atomicAdd(&g_deg8[g * N + d], 1);
    }
}

// ---- K3: chunk-local scans ONLY (no fences, no cross-block ordering) ----
__global__ __launch_bounds__(256) void scans_kernel(int N, int NE) {
    __shared__ int sc[256];
    int t = threadIdx.x;
    int NC8 = (NE + 255) >> 8, NCM = (N + 255) >> 8;
    for (int vb = blockIdx.x; vb < NC8; vb += gridDim.x) {
        int idx = (vb << 8) + t;
        int d = (idx < NE) ? g_deg8[idx] : 0;
        sc[t] = d;
        __syncthreads();
        for (int off = 1; off < 256; off <<= 1) {
            int v = (t >= off) ? sc[t - off] : 0;
            __syncthreads();
            sc[t] += v;
            __syncthreads();
        }
        if (idx < NE) g_rowptr8[idx] = sc[t] - d;  // local exclusive prefix
        if (t == 255) g_bsum[vb] = sc[255];
        __syncthreads();
    }
    for (int vb = blockIdx.x; vb < NCM; vb += gridDim.x) {
        int idx = (vb << 8) + t;
        int d = 0;
        if (idx < N) {
#pragma unroll
            for (int g = 0; g < NGRP; g++) d += g_deg8[g * N + idx];
            g_dinv[idx] = rsqrtf((float)d + 1.0f);  // +1 = self loop
        }
        sc[t] = d;
        __syncthreads();
        for (int off = 1; off < 256; off <<= 1) {
            int v = (t >= off) ? sc[t - off] : 0;
            __syncthreads();
            sc[t] += v;
            __syncthreads();
        }
        if (idx < N) g_mrp[idx] = sc[t] - d;
        if (t == 255) g_bsum2[vb] = sc[255];
        __syncthreads();
    }
}

// ---- K4: per-block prefix over bsum (L2-hot) + add offsets; finalize rowptr8/cursor8/mrp ----
// reads of g_bsum/g_bsum2 are ordered by the kernel boundary -> no fences needed
__global__ __launch_bounds__(256) void addoffs_kernel(int N, int NE, int E) {
    __shared__ int sc[256];
    int t = threadIdx.x;
    int vb = blockIdx.x;
    int NCM = (N + 255) >> 8;
    int ps = 0;
    for (int i = t; i < vb; i += 256) ps += g_bsum[i];
    sc[t] = ps;
    __syncthreads();
    for (int off = 128; off > 0; off >>= 1) {
        if (t < off) sc[t] += sc[t + off];
        __syncthreads();
    }
    int prefix = sc[0];
    __syncthreads();
    int idx = vb * 256 + t;
    if (idx < NE) {
        int base = g_rowptr8[idx] + prefix;
        g_rowptr8[idx] = base;
        g_cursor8[idx] = base;
    }
    if (vb < NCM) {
        int ps2 = 0;
        for (int i = t; i < vb; i += 256) ps2 += g_bsum2[i];
        sc[t] = ps2;
        __syncthreads();
        for (int off = 128; off > 0; off >>= 1) {
            if (t < off) sc[t] += sc[t + off];
            __syncthreads();
        }
        int prefix2 = sc[0];
        if (idx < N) g_mrp[idx] += prefix2;
    }
    if (vb == 0 && t == 0) { g_rowptr8[NE] = E; g_mrp[N] = E; }
}

// ---- K5: scatter edges into group-partitioned CSR (src/dst direct from ei) ----
__global__ __launch_bounds__(256) void scatter_kernel(const void* __restrict__ ei, int N, int E) {
    int e = blockIdx.x * 256 + threadIdx.x;
    if (e < E) {
        int s, d;
        if (g_is64) { const long long* p = (const long long*)ei; s = (int)p[e]; d = (int)p[E + e]; }
        else        { const int* p = (const int*)ei; s = p[e]; d = p[E + e]; }
        int g = blockIdx.x & (NGRP - 1);
        int pos = atomicAdd(&g_cursor8[g * N + d], 1);
        g_csr[pos] = s;
    }
}

// ---- K6: merge group CSR -> node-major mcsr (wave/node) + zprep blocked ----
__global__ __launch_bounds__(256) void mergezp_kernel(const void* __restrict__ z, int N) {
    int gid = blockIdx.x * 256 + threadIdx.x;
    int wid = gid >> 6;
    int lane = threadIdx.x & 63;
    if (wid < N) {
        int mybeg = 0, mycnt = 0;
        if (lane < NGRP) {
            mybeg = g_rowptr8[lane * N + wid];
            mycnt = g_rowptr8[lane * N + wid + 1] - mybeg;
        }
        int incl = mycnt;
#pragma unroll
        for (int off = 1; off < NGRP; off <<= 1) {
            int v = __shfl_up(incl, off, 64);
            if (lane >= off) incl += v;
        }
        int myoff = incl - mycnt;
        int go[NGRP], gb[NGRP];
#pragma unroll
        for (int k = 0; k < NGRP; k++) {
            go[k] = __shfl(myoff, k, 64);
            gb[k] = __shfl(mybeg, k, 64);
        }
        int total = __shfl(incl, NGRP - 1, 64);
        int base = g_mrp[wid];
        for (int i = lane; i < total; i += 64) {
            int g = 0;
#pragma unroll
            for (int k = 1; k < NGRP; k++) g += (i >= go[k]);
            g_mcsr[base + i] = g_csr[gb[g] + i - go[g]];
        }
    }
    if (gid < N * IN_DIM) {
        int node = gid >> 6, c = gid & 63;
        int s = c >> 4, off = c & 15;
        g_agg1[(size_t)s * (N * 16) + node * 16 + off] = loadx(z, gid, g_in_f32) * g_dinv[node];
    }
}

// ---- K7/K9: block-staged sliced aggregation (32 nodes x 1 slice per block) ----
// slice pinned via blockIdx&3 -> per-XCD 3.2MB table stays L2-resident.
template <int LAYER2>
__global__ __launch_bounds__(256) void aggslc_kernel(void* __restrict__ outp, int N) {
    __shared__ int rp[NPB + 1];
    __shared__ int eidx[ECAP];
    int s = blockIdx.x & (NSLC - 1);
    int n0 = (blockIdx.x >> 2) * NPB;
    int t = threadIdx.x;
    if (t <= NPB) {
        int idx = n0 + t;
        rp[t] = g_mrp[idx <= N ? idx : N];
    }
    __syncthreads();
    int base = rp[0];
    int range = rp[NPB] - base;
    bool staged = (range <= ECAP);
    if (staged) {
        for (int i = t; i < range; i += 256) eidx[i] = g_mcsr[base + i];
    }
    __syncthreads();
    const float* tab = (LAYER2 ? g_hs1 : g_agg1) + (size_t)s * ((size_t)N * 16);
    int lane = t & 63;
    int w8 = (t >> 6) * 8;
    int col = lane & 15, eslot = lane >> 4;
    float res[8];
#pragma unroll
    for (int k = 0; k < 8; k++) {
        int jb = rp[w8 + k] - base + eslot;
        int je = rp[w8 + k + 1] - base;
        float a0 = 0.f, a1 = 0.f, a2 = 0.f, a3 = 0.f;
        int j = jb;
        if (staged) {
            for (; j + 12 < je; j += 16) {
                int i0 = eidx[j], i1 = eidx[j + 4], i2 = eidx[j + 8], i3 = eidx[j + 12];
                a0 += tab[i0 * 16 + col];
                a1 += tab[i1 * 16 + col];
                a2 += tab[i2 * 16 + col];
                a3 += tab[i3 * 16 + col];
            }
            for (; j < je; j += 4) a0 += tab[eidx[j] * 16 + col];
        } else {
            for (; j < je; j += 4) a0 += tab[g_mcsr[base + j] * 16 + col];
        }
        float a = (a0 + a1) + (a2 + a3);
        a += __shfl_xor(a, 16, 64);
        a += __shfl_xor(a, 32, 64);
        res[k] = a;
    }
    if (lane < 16) {
#pragma unroll
        for (int k = 0; k < 8; k++) {
            int nk = n0 + w8 + k;
            if (nk < N) {
                float v = (res[k] + tab[(size_t)nk * 16 + col]) * g_dinv[nk];
                if (LAYER2) {
                    v += g_b2f[s * 16 + col];
                    int oc = nk * 64 + s * 16 + col;
                    if (g_in_f32) ((float*)outp)[oc] = v;
                    else ((__hip_bfloat16*)outp)[oc] = __float2bfloat16(v);
                } else {
                    g_hs1[(size_t)s * ((size_t)N * 16) + nk * 16 + col] = v;
                }
            }
        }
    }
}

// ---- K8: FUSED MLP per 64-row block: hs2 = (relu(aggz@W1+b1))@W2 * dinv ----
// 64 rows/block doubles FMA per W-load / LDS-load: gemm1 = 32 FMA/thread/k-iter,
// gemm2 = 64 FMA/thread/k4-iter -> latency chains covered by ILP.
// Single UNION LDS buffer [64][132] (33.8 KB): input (k<64) during gemm1, then h (k<128).
__global__ __launch_bounds__(256) void gemm_fused_kernel(int N) {
    __shared__ __align__(16) float B[64 * 132];   // 33792 B
    int t = threadIdx.x;
    int row0 = blockIdx.x * 64;
    // stage aggz (blocked [4][N][16]) row-major into B: 1024 float4 = 4/thread
#pragma unroll
    for (int s = 0; s < 4; s++) {
        int i = t + s * 256;
        int r = i >> 4, k4 = i & 15;
        int row = row0 + r;
        int g = k4 >> 2, off = (k4 & 3) * 4;
        float4 v = make_float4(0.f, 0.f, 0.f, 0.f);
        if (row < N) v = *(const float4*)&g_hs1[(size_t)g * (N * 16) + row * 16 + off];
        *(float4*)&B[r * 132 + k4 * 4] = v;
    }
    __syncthreads();
    // gemm1: 32 colgroups x 8 rowgroups, 8x4 micro-tile -> registers
    int cg1 = t & 31, rg1 = t >> 5;
    int c1 = cg1 * 4, r1 = rg1 * 8;
    float acc1[8][4] = {};
#pragma unroll 4
    for (int k = 0; k < IN_DIM; k++) {
        float b[4];
        *(float4*)b = *(const float4*)&g_W1f[k * HID_DIM + c1];
        float a[8];
#pragma unroll
        for (int i = 0; i < 8; i++) a[i] = B[(r1 + i) * 132 + k];
#pragma unroll
        for (int i = 0; i < 8; i++)
#pragma unroll
            for (int j = 0; j < 4; j++) acc1[i][j] = fmaf(a[i], b[j], acc1[i][j]);
    }
    __syncthreads();   // all input reads complete before h overwrites the buffer
    {
        float4 bias = *(const float4*)&g_b1f[c1];
#pragma unroll
        for (int i = 0; i < 8; i++) {
            float4 v;
            v.x = fmaxf(acc1[i][0] + bias.x, 0.f);
            v.y = fmaxf(acc1[i][1] + bias.y, 0.f);
            v.z = fmaxf(acc1[i][2] + bias.z, 0.f);
            v.w = fmaxf(acc1[i][3] + bias.w, 0.f);
            *(float4*)&B[(r1 + i) * 132 + c1] = v;
        }
    }
    __syncthreads();
    // gemm2: 16 colgroups x 16 rowgroups, 4x4 micro-tile; K=128 via float4 chunks of B
    {
        int cg = t & 15, rg = t >> 4;
        int c0 = cg * 4, r0 = rg * 4;
        float acc[4][4] = {};
#pragma unroll 2
        for (int k4 = 0; k4 < 32; k4++) {
            float av[4][4];
#pragma unroll
            for (int i = 0; i < 4; i++)
                *(float4*)av[i] = *(const float4*)&B[(r0 + i) * 132 + k4 * 4];
#pragma unroll
            for (int jj = 0; jj < 4; jj++) {
                float b[4];
                *(float4*)b = *(const float4*)&g_W2f[(k4 * 4 + jj) * OUT_DIM + c0];
#pragma unroll
                for (int i = 0; i < 4; i++)
#pragma unroll
                    for (int j = 0; j < 4; j++) acc[i][j] = fmaf(av[i][jj], b[j], acc[i][j]);
            }
        }
        int g = cg >> 2, off = (cg & 3) * 4;  // blocked output [4][N][16]
#pragma unroll
        for (int i = 0; i < 4; i++) {
            int row = row0 + r0 + i;
            if (row < N) {
                float dn = g_dinv[row];
                float4 v;
                v.x = acc[i][0] * dn;
                v.y = acc[i][1] * dn;
                v.z = acc[i][2] * dn;
                v.w = acc[i][3] * dn;
                *(float4*)&g_hs1[(size_t)g * (N * 16) + row * 16 + off] = v;
            }
        }
    }
}

extern "C" void kernel_launch(void* const* d_in, const int* in_sizes, int n_in,
                              void* d_out, int out_size, void* d_ws, size_t ws_size,
                              hipStream_t stream) {
    const void* z  = d_in[0];
    const void* ei = d_in[1];
    const void* W1 = d_in[2];
    const void* b1 = d_in[3];
    const void* W2 = d_in[4];
    const void* b2 = d_in[5];

    const int N = in_sizes[0] / IN_DIM;  // 50000
    const int E = in_sizes[1] / 2;       // 800000
    const int NE = NGRP * N;             // 400000
    const int NC8 = (NE + 255) / 256;    // 1563
    const int aggblocks = NSLC * ((N + NPB - 1) / NPB);  // 6252

    zerodet_kernel<<<NC8, 256, 0, stream>>>((const unsigned short*)z, (const unsigned int*)ei, NE, E);
    degprep_kernel<<<(E + 255) / 256, 256, 0, stream>>>(ei, W1, b1, W2, b2, N, E);
    scans_kernel<<<NC8, 256, 0, stream>>>(N, NE);
    addoffs_kernel<<<NC8, 256, 0, stream>>>(N, NE, E);
    scatter_kernel<<<(E + 255) / 256, 256, 0, stream>>>(ei, N, E);
    mergezp_kernel<<<(N * 64 + 255) / 256, 256, 0, stream>>>(z, N);

    aggslc_kernel<0><<<aggblocks, 256, 0, stream>>>(d_out, N);
    gemm_fused_kernel<<<(N + 63) / 64, 256, 0, stream>>>(N);
    aggslc_kernel<1><<<aggblocks, 256, 0, stream>>>(d_out, N);
}

// Round 15
// 275.228 us; speedup vs baseline: 1.5615x; 1.0948x over previous
//
#include <hip/hip_runtime.h>
#include <hip/hip_bf16.h>

#define N_NODES 50000
#define N_EDGES 800000
#define IN_DIM 64
#define HID_DIM 128
#define OUT_DIM 64
#define NGRP 8
#define NSLC 4                                // feature slices (16 floats = 64B line)
#define NPB 64                                // nodes per agg block (16/wave x 4 waves)
#define ECAP 2048                             // staged edge cap per block
#define NE8 (NGRP * N_NODES)                  // 400000
#define NC8C ((NE8 + 255) / 256)              // 1563 scan chunks (group-major)
#define NCMC ((N_NODES + 255) / 256)          // 196 scan chunks (merged)

// ---- device-global scratch ----
__device__ int g_in_f32;
__device__ int g_is64;
__device__ int g_csr[N_EDGES];                // group-major partitioned CSR
__device__ int g_mcsr[N_EDGES];               // merged node-major CSR
__device__ int g_deg8[NE8];                   // [g][v]
__device__ int g_rowptr8[NE8 + 1];
__device__ int g_cursor8[NE8];
__device__ int g_mrp[N_NODES + 1];
__device__ int g_bsum[NC8C];
__device__ int g_bsum2[NCMC];
__device__ float g_dinv[N_NODES];
__device__ __align__(16) float g_W1f[IN_DIM * HID_DIM];
__device__ __align__(16) float g_W2f[HID_DIM * OUT_DIM];
__device__ __align__(16) float g_b1f[HID_DIM];
__device__ __align__(16) float g_b2f[OUT_DIM];
// g_hs1: aggz out blocked [4][N][16]; then hs2 blocked [4][N][16] (in-place per-row swap in gemm_fused)
__device__ __align__(16) float g_hs1[(size_t)N_NODES * IN_DIM];
// g_agg1: zb blocked [4][N][16] (dinv-scaled z)
__device__ __align__(16) float g_agg1[(size_t)N_NODES * IN_DIM];

__device__ __forceinline__ float loadx(const void* p, int i, int f32) {
    if (f32) return ((const float*)p)[i];
    unsigned int u = ((unsigned int)((const unsigned short*)p)[i]) << 16;
    return __uint_as_float(u);
}

// ---- K1: zero deg8 (grid) + dtype/index detect (block 0) ----
__global__ __launch_bounds__(256) void zerodet_kernel(const unsigned short* __restrict__ zw,
                                                      const unsigned int* __restrict__ ew,
                                                      int NE, int E) {
    int idx = blockIdx.x * 256 + threadIdx.x;
    if (idx < NE) g_deg8[idx] = 0;
    if (blockIdx.x == 0) {
        __shared__ int flags[2];
        int t = threadIdx.x;
        if (t < 2) flags[t] = 0;
        __syncthreads();
        int hit = 0;
        for (int k = 0; k < 64; k++) {
            int i = 2 * ((t * 64 + k) * 97);
            if (((zw[i] >> 7) & 0xFF) == 0xFF) hit = 1;
        }
        if (hit) atomicOr(&flags[0], 1);
        int nz = 0;
        int step = E / 4096;
        for (int k = 0; k < 4; k++) {
            int i = 1 + 2 * ((t * 4 + k) * step);
            if (ew[i] != 0) nz = 1;
        }
        if (nz) atomicOr(&flags[1], 1);
        __syncthreads();
        if (t == 0) { g_in_f32 = flags[0]; g_is64 = (flags[1] == 0) ? 1 : 0; }
    }
}

// ---- K2: per-group degree count (dst read direct from ei) + weight/bias f32 prep ----
__global__ __launch_bounds__(256) void degprep_kernel(const void* __restrict__ ei,
                                                      const void* __restrict__ W1, const void* __restrict__ b1,
                                                      const void* __restrict__ W2, const void* __restrict__ b2,
                                                      int N, int E) {
    int e = blockIdx.x * 256 + threadIdx.x;
    int f32 = g_in_f32;
    if (e < IN_DIM * HID_DIM) g_W1f[e] = loadx(W1, e, f32);
    if (e < HID_DIM * OUT_DIM) g_W2f[e] = loadx(W2, e, f32);
    if (e < HID_DIM) g_b1f[e] = loadx(b1, e, f32);
    if (e < OUT_DIM) g_b2f[e] = loadx(b2, e, f32);
    if (e < E) {
        int d = g_is64 ? (int)((const long long*)ei)[E + e] : ((const int*)ei)[E + e];
        int g = blockIdx.x & (NGRP - 1);          // round-robin -> XCD-local counters
        atomicAdd(&g_deg8[g * N + d], 1);
    }
}

// ---- K3: chunk-local scans ONLY (no fences, no cross-block ordering) ----
__global__ __launch_bounds__(256) void scans_kernel(int N, int NE) {
    __shared__ int sc[256];
    int t = threadIdx.x;
    int NC8 = (NE + 255) >> 8, NCM = (N + 255) >> 8;
    for (int vb = blockIdx.x; vb < NC8; vb += gridDim.x) {
        int idx = (vb << 8) + t;
        int d = (idx < NE) ? g_deg8[idx] : 0;
        sc[t] = d;
        __syncthreads();
        for (int off = 1; off < 256; off <<= 1) {
            int v = (t >= off) ? sc[t - off] : 0;
            __syncthreads();
            sc[t] += v;
            __syncthreads();
        }
        if (idx < NE) g_rowptr8[idx] = sc[t] - d;  // local exclusive prefix
        if (t == 255) g_bsum[vb] = sc[255];
        __syncthreads();
    }
    for (int vb = blockIdx.x; vb < NCM; vb += gridDim.x) {
        int idx = (vb << 8) + t;
        int d = 0;
        if (idx < N) {
#pragma unroll
            for (int g = 0; g < NGRP; g++) d += g_deg8[g * N + idx];
            g_dinv[idx] = rsqrtf((float)d + 1.0f);  // +1 = self loop
        }
        sc[t] = d;
        __syncthreads();
        for (int off = 1; off < 256; off <<= 1) {
            int v = (t >= off) ? sc[t - off] : 0;
            __syncthreads();
            sc[t] += v;
            __syncthreads();
        }
        if (idx < N) g_mrp[idx] = sc[t] - d;
        if (t == 255) g_bsum2[vb] = sc[255];
        __syncthreads();
    }
}

// ---- K4: per-block prefix over bsum (L2-hot) + add offsets; finalize rowptr8/cursor8/mrp ----
// reads of g_bsum/g_bsum2 are ordered by the kernel boundary -> no fences needed
__global__ __launch_bounds__(256) void addoffs_kernel(int N, int NE, int E) {
    __shared__ int sc[256];
    int t = threadIdx.x;
    int vb = blockIdx.x;
    int NCM = (N + 255) >> 8;
    int ps = 0;
    for (int i = t; i < vb; i += 256) ps += g_bsum[i];
    sc[t] = ps;
    __syncthreads();
    for (int off = 128; off > 0; off >>= 1) {
        if (t < off) sc[t] += sc[t + off];
        __syncthreads();
    }
    int prefix = sc[0];
    __syncthreads();
    int idx = vb * 256 + t;
    if (idx < NE) {
        int base = g_rowptr8[idx] + prefix;
        g_rowptr8[idx] = base;
        g_cursor8[idx] = base;
    }
    if (vb < NCM) {
        int ps2 = 0;
        for (int i = t; i < vb; i += 256) ps2 += g_bsum2[i];
        sc[t] = ps2;
        __syncthreads();
        for (int off = 128; off > 0; off >>= 1) {
            if (t < off) sc[t] += sc[t + off];
            __syncthreads();
        }
        int prefix2 = sc[0];
        if (idx < N) g_mrp[idx] += prefix2;
    }
    if (vb == 0 && t == 0) { g_rowptr8[NE] = E; g_mrp[N] = E; }
}

// ---- K5: scatter edges into group-partitioned CSR (src/dst direct from ei) ----
__global__ __launch_bounds__(256) void scatter_kernel(const void* __restrict__ ei, int N, int E) {
    int e = blockIdx.x * 256 + threadIdx.x;
    if (e < E) {
        int s, d;
        if (g_is64) { const long long* p = (const long long*)ei; s = (int)p[e]; d = (int)p[E + e]; }
        else        { const int* p = (const int*)ei; s = p[e]; d = p[E + e]; }
        int g = blockIdx.x & (NGRP - 1);
        int pos = atomicAdd(&g_cursor8[g * N + d], 1);
        g_csr[pos] = s;
    }
}

// ---- K6: merge group CSR -> node-major mcsr (wave/node) + zprep blocked ----
__global__ __launch_bounds__(256) void mergezp_kernel(const void* __restrict__ z, int N) {
    int gid = blockIdx.x * 256 + threadIdx.x;
    int wid = gid >> 6;
    int lane = threadIdx.x & 63;
    if (wid < N) {
        int mybeg = 0, mycnt = 0;
        if (lane < NGRP) {
            mybeg = g_rowptr8[lane * N + wid];
            mycnt = g_rowptr8[lane * N + wid + 1] - mybeg;
        }
        int incl = mycnt;
#pragma unroll
        for (int off = 1; off < NGRP; off <<= 1) {
            int v = __shfl_up(incl, off, 64);
            if (lane >= off) incl += v;
        }
        int myoff = incl - mycnt;
        int go[NGRP], gb[NGRP];
#pragma unroll
        for (int k = 0; k < NGRP; k++) {
            go[k] = __shfl(myoff, k, 64);
            gb[k] = __shfl(mybeg, k, 64);
        }
        int total = __shfl(incl, NGRP - 1, 64);
        int base = g_mrp[wid];
        for (int i = lane; i < total; i += 64) {
            int g = 0;
#pragma unroll
            for (int k = 1; k < NGRP; k++) g += (i >= go[k]);
            g_mcsr[base + i] = g_csr[gb[g] + i - go[g]];
        }
    }
    if (gid < N * IN_DIM) {
        int node = gid >> 6, c = gid & 63;
        int s = c >> 4, off = c & 15;
        g_agg1[(size_t)s * (N * 16) + node * 16 + off] = loadx(z, gid, g_in_f32) * g_dinv[node];
    }
}

// ---- K7/K9: lane-per-(node,col4) sliced aggregation: 64 nodes x 1 slice per block ----
// lane = (node 0..15, col4 0..3): serial float4 gather per lane -> NO cross-lane
// reduce, b128 loads (16 rows/instr/wave), ~0.5 issue/edge.
// slice pinned via blockIdx&3 -> per-XCD 3.2MB table stays L2-resident.
template <int LAYER2>
__global__ __launch_bounds__(256) void aggslc_kernel(void* __restrict__ outp, int N) {
    __shared__ int rp[NPB + 1];
    __shared__ int eidx[ECAP];
    int s = blockIdx.x & (NSLC - 1);
    int n0 = (blockIdx.x >> 2) * NPB;
    int t = threadIdx.x;
    if (t <= NPB) {
        int idx = n0 + t;
        rp[t] = g_mrp[idx <= N ? idx : N];
    }
    __syncthreads();
    int base = rp[0];
    int range = rp[NPB] - base;
    bool staged = (range <= ECAP);
    if (staged) {
        for (int i = t; i < range; i += 256) eidx[i] = g_mcsr[base + i];
    }
    __syncthreads();
    const float* tab = (LAYER2 ? g_hs1 : g_agg1) + (size_t)s * ((size_t)N * 16);
    int lane = t & 63;
    int nsub = (t >> 6) * 16 + (lane >> 2);   // node index within block (0..63)
    int col4 = lane & 3;                      // float4 column (4 lanes per node)
    int nk = n0 + nsub;
    if (nk >= N) return;
    float4 a0 = make_float4(0.f, 0.f, 0.f, 0.f);
    float4 a1 = make_float4(0.f, 0.f, 0.f, 0.f);
    int jb = rp[nsub] - base;
    int je = rp[nsub + 1] - base;
    if (staged) {
        int j = jb;
        for (; j + 1 < je; j += 2) {
            int i0 = eidx[j], i1 = eidx[j + 1];
            float4 v0 = *(const float4*)&tab[(size_t)i0 * 16 + col4 * 4];
            float4 v1 = *(const float4*)&tab[(size_t)i1 * 16 + col4 * 4];
            a0.x += v0.x; a0.y += v0.y; a0.z += v0.z; a0.w += v0.w;
            a1.x += v1.x; a1.y += v1.y; a1.z += v1.z; a1.w += v1.w;
        }
        if (j < je) {
            float4 v0 = *(const float4*)&tab[(size_t)eidx[j] * 16 + col4 * 4];
            a0.x += v0.x; a0.y += v0.y; a0.z += v0.z; a0.w += v0.w;
        }
    } else {  // essentially-never fallback: direct global index walk
        for (int j = jb; j < je; j++) {
            float4 v0 = *(const float4*)&tab[(size_t)g_mcsr[base + j] * 16 + col4 * 4];
            a0.x += v0.x; a0.y += v0.y; a0.z += v0.z; a0.w += v0.w;
        }
    }
    float4 self = *(const float4*)&tab[(size_t)nk * 16 + col4 * 4];
    float dn = g_dinv[nk];
    float4 v;
    v.x = (a0.x + a1.x + self.x) * dn;
    v.y = (a0.y + a1.y + self.y) * dn;
    v.z = (a0.z + a1.z + self.z) * dn;
    v.w = (a0.w + a1.w + self.w) * dn;
    if (LAYER2) {
        float4 bias = *(const float4*)&g_b2f[s * 16 + col4 * 4];
        v.x += bias.x; v.y += bias.y; v.z += bias.z; v.w += bias.w;
        int oc = nk * 64 + s * 16 + col4 * 4;
        if (g_in_f32) {
            *(float4*)&((float*)outp)[oc] = v;
        } else {
            __hip_bfloat16* o = (__hip_bfloat16*)outp + oc;
            o[0] = __float2bfloat16(v.x);
            o[1] = __float2bfloat16(v.y);
            o[2] = __float2bfloat16(v.z);
            o[3] = __float2bfloat16(v.w);
        }
    } else {
        *(float4*)&g_hs1[(size_t)s * ((size_t)N * 16) + nk * 16 + col4 * 4] = v;
    }
}

// ---- K8: FUSED MLP per 64-row block: hs2 = (relu(aggz@W1+b1))@W2 * dinv ----
// 64 rows/block doubles FMA per W-load / LDS-load: gemm1 = 32 FMA/thread/k-iter,
// gemm2 = 64 FMA/thread/k4-iter -> latency chains covered by ILP.
// Single UNION LDS buffer [64][132] (33.8 KB): input (k<64) during gemm1, then h (k<128).
__global__ __launch_bounds__(256) void gemm_fused_kernel(int N) {
    __shared__ __align__(16) float B[64 * 132];   // 33792 B
    int t = threadIdx.x;
    int row0 = blockIdx.x * 64;
    // stage aggz (blocked [4][N][16]) row-major into B: 1024 float4 = 4/thread
#pragma unroll
    for (int s = 0; s < 4; s++) {
        int i = t + s * 256;
        int r = i >> 4, k4 = i & 15;
        int row = row0 + r;
        int g = k4 >> 2, off = (k4 & 3) * 4;
        float4 v = make_float4(0.f, 0.f, 0.f, 0.f);
        if (row < N) v = *(const float4*)&g_hs1[(size_t)g * (N * 16) + row * 16 + off];
        *(float4*)&B[r * 132 + k4 * 4] = v;
    }
    __syncthreads();
    // gemm1: 32 colgroups x 8 rowgroups, 8x4 micro-tile -> registers
    int cg1 = t & 31, rg1 = t >> 5;
    int c1 = cg1 * 4, r1 = rg1 * 8;
    float acc1[8][4] = {};
#pragma unroll 4
    for (int k = 0; k < IN_DIM; k++) {
        float b[4];
        *(float4*)b = *(const float4*)&g_W1f[k * HID_DIM + c1];
        float a[8];
#pragma unroll
        for (int i = 0; i < 8; i++) a[i] = B[(r1 + i) * 132 + k];
#pragma unroll
        for (int i = 0; i < 8; i++)
#pragma unroll
            for (int j = 0; j < 4; j++) acc1[i][j] = fmaf(a[i], b[j], acc1[i][j]);
    }
    __syncthreads();   // all input reads complete before h overwrites the buffer
    {
        float4 bias = *(const float4*)&g_b1f[c1];
#pragma unroll
        for (int i = 0; i < 8; i++) {
            float4 v;
            v.x = fmaxf(acc1[i][0] + bias.x, 0.f);
            v.y = fmaxf(acc1[i][1] + bias.y, 0.f);
            v.z = fmaxf(acc1[i][2] + bias.z, 0.f);
            v.w = fmaxf(acc1[i][3] + bias.w, 0.f);
            *(float4*)&B[(r1 + i) * 132 + c1] = v;
        }
    }
    __syncthreads();
    // gemm2: 16 colgroups x 16 rowgroups, 4x4 micro-tile; K=128 via float4 chunks of B
    {
        int cg = t & 15, rg = t >> 4;
        int c0 = cg * 4, r0 = rg * 4;
        float acc[4][4] = {};
#pragma unroll 2
        for (int k4 = 0; k4 < 32; k4++) {
            float av[4][4];
#pragma unroll
            for (int i = 0; i < 4; i++)
                *(float4*)av[i] = *(const float4*)&B[(r0 + i) * 132 + k4 * 4];
#pragma unroll
            for (int jj = 0; jj < 4; jj++) {
                float b[4];
                *(float4*)b = *(const float4*)&g_W2f[(k4 * 4 + jj) * OUT_DIM + c0];
#pragma unroll
                for (int i = 0; i < 4; i++)
#pragma unroll
                    for (int j = 0; j < 4; j++) acc[i][j] = fmaf(av[i][jj], b[j], acc[i][j]);
            }
        }
        int g = cg >> 2, off = (cg & 3) * 4;  // blocked output [4][N][16]
#pragma unroll
        for (int i = 0; i < 4; i++) {
            int row = row0 + r0 + i;
            if (row < N) {
                float dn = g_dinv[row];
                float4 v;
                v.x = acc[i][0] * dn;
                v.y = acc[i][1] * dn;
                v.z = acc[i][2] * dn;
                v.w = acc[i][3] * dn;
                *(float4*)&g_hs1[(size_t)g * (N * 16) + row * 16 + off] = v;
            }
        }
    }
}

extern "C" void kernel_launch(void* const* d_in, const int* in_sizes, int n_in,
                              void* d_out, int out_size, void* d_ws, size_t ws_size,
                              hipStream_t stream) {
    const void* z  = d_in[0];
    const void* ei = d_in[1];
    const void* W1 = d_in[2];
    const void* b1 = d_in[3];
    const void* W2 = d_in[4];
    const void* b2 = d_in[5];

    const int N = in_sizes[0] / IN_DIM;  // 50000
    const int E = in_sizes[1] / 2;       // 800000
    const int NE = NGRP * N;             // 400000
    const int NC8 = (NE + 255) / 256;    // 1563
    const int aggblocks = NSLC * ((N + NPB - 1) / NPB);  // 3128

    zerodet_kernel<<<NC8, 256, 0, stream>>>((const unsigned short*)z, (const unsigned int*)ei, NE, E);
    degprep_kernel<<<(E + 255) / 256, 256, 0, stream>>>(ei, W1, b1, W2, b2, N, E);
    scans_kernel<<<NC8, 256, 0, stream>>>(N, NE);
    addoffs_kernel<<<NC8, 256, 0, stream>>>(N, NE, E);
    scatter_kernel<<<(E + 255) / 256, 256, 0, stream>>>(ei, N, E);
    mergezp_kernel<<<(N * 64 + 255) / 256, 256, 0, stream>>>(z, N);

    aggslc_kernel<0><<<aggblocks, 256, 0, stream>>>(d_out, N);
    gemm_fused_kernel<<<(N + 63) / 64, 256, 0, stream>>>(N);
    aggslc_kernel<1><<<aggblocks, 256, 0, stream>>>(d_out, N);
}

// Round 16
// 267.388 us; speedup vs baseline: 1.6073x; 1.0293x over previous
//
#include <hip/hip_runtime.h>
#include <hip/hip_bf16.h>

#define N_NODES 50000
#define N_EDGES 800000
#define IN_DIM 64
#define HID_DIM 128
#define OUT_DIM 64
#define NGRP 8
#define NSLC 4                                // feature slices (16 floats = 64B line)
#define NPB 64                                // nodes per agg block (16/wave x 4 waves)
#define ECAP 2048                             // staged edge cap per block
#define NE8 (NGRP * N_NODES)                  // 400000
#define NC8C ((NE8 + 255) / 256)              // 1563 scan chunks (group-major)
#define NCMC ((N_NODES + 255) / 256)          // 196 scan chunks (merged)

// ---- device-global scratch (zero-initialized at module load; deg8 re-zeroed
//      by addoffs after its last use each iteration) ----
__device__ int g_in_f32;
__device__ int g_is64;
__device__ int g_csr[N_EDGES];                // group-major partitioned CSR
__device__ int g_mcsr[N_EDGES];               // merged node-major CSR
__device__ int g_deg8[NE8];                   // [g][v]
__device__ int g_rowptr8[NE8 + 1];
__device__ int g_cursor8[NE8];
__device__ int g_mrp[N_NODES + 1];
__device__ int g_bsum[NC8C];
__device__ int g_bsum2[NCMC];
__device__ float g_dinv[N_NODES];
__device__ __align__(16) float g_W1f[IN_DIM * HID_DIM];
__device__ __align__(16) float g_W2f[HID_DIM * OUT_DIM];
__device__ __align__(16) float g_b1f[HID_DIM];
__device__ __align__(16) float g_b2f[OUT_DIM];
// g_hs1: aggz out blocked [4][N][16]; then hs2 blocked [4][N][16] (in-place per-row swap in gemm_fused)
__device__ __align__(16) float g_hs1[(size_t)N_NODES * IN_DIM];
// g_agg1: zb blocked [4][N][16] (dinv-scaled z)
__device__ __align__(16) float g_agg1[(size_t)N_NODES * IN_DIM];

__device__ __forceinline__ float loadx(const void* p, int i, int f32) {
    if (f32) return ((const float*)p)[i];
    unsigned int u = ((unsigned int)((const unsigned short*)p)[i]) << 16;
    return __uint_as_float(u);
}

// ---- K1: per-group degree count + detect (per-block is64; block 0 publishes flags) ----
// deg8 is zero on entry: .bss init on first run, addoffs re-zeroes each iteration.
__global__ __launch_bounds__(256) void degprep_kernel(const void* __restrict__ ei,
                                                      const unsigned short* __restrict__ zw,
                                                      int N, int E) {
    __shared__ int s_nz, s_f32;
    int t = threadIdx.x;
    if (t == 0) { s_nz = 0; s_f32 = 0; }
    __syncthreads();
    // per-block is64 detect: int64 indices < 2^32 -> all odd words zero (deterministic)
    const unsigned int* ew = (const unsigned int*)ei;
    int nz = 0;
    int step = E / 4096;
    for (int k = 0; k < 4; k++) {
        int i = 1 + 2 * ((t * 4 + k) * step);
        if (ew[i] != 0) nz = 1;
    }
    if (nz) atomicOr(&s_nz, 1);
    if (blockIdx.x == 0) {
        // robust f32 detect (16K samples), published for downstream kernels
        int hit = 0;
        for (int k = 0; k < 64; k++) {
            int i = 2 * ((t * 64 + k) * 97);
            if (((zw[i] >> 7) & 0xFF) == 0xFF) hit = 1;
        }
        if (hit) atomicOr(&s_f32, 1);
    }
    __syncthreads();
    int is64 = (s_nz == 0);
    if (blockIdx.x == 0 && t == 0) { g_in_f32 = s_f32; g_is64 = is64; }
    int e = blockIdx.x * 256 + t;
    if (e < E) {
        int d = is64 ? (int)((const long long*)ei)[E + e] : ((const int*)ei)[E + e];
        int g = blockIdx.x & (NGRP - 1);          // round-robin -> XCD-local counters
        atomicAdd(&g_deg8[g * N + d], 1);
    }
}

// ---- K2: chunk-local scans ONLY (no fences, no cross-block ordering) ----
__global__ __launch_bounds__(256) void scans_kernel(int N, int NE) {
    __shared__ int sc[256];
    int t = threadIdx.x;
    int NC8 = (NE + 255) >> 8, NCM = (N + 255) >> 8;
    for (int vb = blockIdx.x; vb < NC8; vb += gridDim.x) {
        int idx = (vb << 8) + t;
        int d = (idx < NE) ? g_deg8[idx] : 0;
        sc[t] = d;
        __syncthreads();
        for (int off = 1; off < 256; off <<= 1) {
            int v = (t >= off) ? sc[t - off] : 0;
            __syncthreads();
            sc[t] += v;
            __syncthreads();
        }
        if (idx < NE) g_rowptr8[idx] = sc[t] - d;  // local exclusive prefix
        if (t == 255) g_bsum[vb] = sc[255];
        __syncthreads();
    }
    for (int vb = blockIdx.x; vb < NCM; vb += gridDim.x) {
        int idx = (vb << 8) + t;
        int d = 0;
        if (idx < N) {
#pragma unroll
            for (int g = 0; g < NGRP; g++) d += g_deg8[g * N + idx];
            g_dinv[idx] = rsqrtf((float)d + 1.0f);  // +1 = self loop
        }
        sc[t] = d;
        __syncthreads();
        for (int off = 1; off < 256; off <<= 1) {
            int v = (t >= off) ? sc[t - off] : 0;
            __syncthreads();
            sc[t] += v;
            __syncthreads();
        }
        if (idx < N) g_mrp[idx] = sc[t] - d;
        if (t == 255) g_bsum2[vb] = sc[255];
        __syncthreads();
    }
}

// ---- K3: per-block prefix over bsum (L2-hot) + add offsets + deg8 self-clean ----
// reads of g_bsum/g_bsum2 are ordered by the kernel boundary -> no fences needed;
// deg8 is dead after scans, so zeroing here leaves it clean for the next replay.
__global__ __launch_bounds__(256) void addoffs_kernel(int N, int NE, int E) {
    __shared__ int sc[256];
    int t = threadIdx.x;
    int vb = blockIdx.x;
    int NCM = (N + 255) >> 8;
    int ps = 0;
    for (int i = t; i < vb; i += 256) ps += g_bsum[i];
    sc[t] = ps;
    __syncthreads();
    for (int off = 128; off > 0; off >>= 1) {
        if (t < off) sc[t] += sc[t + off];
        __syncthreads();
    }
    int prefix = sc[0];
    __syncthreads();
    int idx = vb * 256 + t;
    if (idx < NE) {
        int base = g_rowptr8[idx] + prefix;
        g_rowptr8[idx] = base;
        g_cursor8[idx] = base;
        g_deg8[idx] = 0;                      // self-clean for next iteration
    }
    if (vb < NCM) {
        int ps2 = 0;
        for (int i = t; i < vb; i += 256) ps2 += g_bsum2[i];
        sc[t] = ps2;
        __syncthreads();
        for (int off = 128; off > 0; off >>= 1) {
            if (t < off) sc[t] += sc[t + off];
            __syncthreads();
        }
        int prefix2 = sc[0];
        if (idx < N) g_mrp[idx] += prefix2;
    }
    if (vb == 0 && t == 0) { g_rowptr8[NE] = E; g_mrp[N] = E; }
}

// ---- K4: scatter edges into group-partitioned CSR (src/dst direct from ei) ----
__global__ __launch_bounds__(256) void scatter_kernel(const void* __restrict__ ei, int N, int E) {
    int e = blockIdx.x * 256 + threadIdx.x;
    if (e < E) {
        int s, d;
        if (g_is64) { const long long* p = (const long long*)ei; s = (int)p[e]; d = (int)p[E + e]; }
        else        { const int* p = (const int*)ei; s = p[e]; d = p[E + e]; }
        int g = blockIdx.x & (NGRP - 1);
        int pos = atomicAdd(&g_cursor8[g * N + d], 1);
        if (pos < E) g_csr[pos] = s;          // guard vs corrupted replay state
    }
}

// ---- K5: merge group CSR -> node-major mcsr (wave/node) + zprep blocked + W/b f32 prep ----
__global__ __launch_bounds__(256) void mergezp_kernel(const void* __restrict__ z,
                                                      const void* __restrict__ W1, const void* __restrict__ b1,
                                                      const void* __restrict__ W2, const void* __restrict__ b2,
                                                      int N) {
    int gid = blockIdx.x * 256 + threadIdx.x;
    int f32 = g_in_f32;
    if (gid < IN_DIM * HID_DIM) g_W1f[gid] = loadx(W1, gid, f32);
    if (gid < HID_DIM * OUT_DIM) g_W2f[gid] = loadx(W2, gid, f32);
    if (gid < HID_DIM) g_b1f[gid] = loadx(b1, gid, f32);
    if (gid < OUT_DIM) g_b2f[gid] = loadx(b2, gid, f32);
    int wid = gid >> 6;
    int lane = threadIdx.x & 63;
    if (wid < N) {
        int mybeg = 0, mycnt = 0;
        if (lane < NGRP) {
            mybeg = g_rowptr8[lane * N + wid];
            mycnt = g_rowptr8[lane * N + wid + 1] - mybeg;
        }
        int incl = mycnt;
#pragma unroll
        for (int off = 1; off < NGRP; off <<= 1) {
            int v = __shfl_up(incl, off, 64);
            if (lane >= off) incl += v;
        }
        int myoff = incl - mycnt;
        int go[NGRP], gb[NGRP];
#pragma unroll
        for (int k = 0; k < NGRP; k++) {
            go[k] = __shfl(myoff, k, 64);
            gb[k] = __shfl(mybeg, k, 64);
        }
        int total = __shfl(incl, NGRP - 1, 64);
        int base = g_mrp[wid];
        for (int i = lane; i < total; i += 64) {
            int g = 0;
#pragma unroll
            for (int k = 1; k < NGRP; k++) g += (i >= go[k]);
            g_mcsr[base + i] = g_csr[gb[g] + i - go[g]];
        }
    }
    if (gid < N * IN_DIM) {
        int node = gid >> 6, c = gid & 63;
        int s = c >> 4, off = c & 15;
        g_agg1[(size_t)s * (N * 16) + node * 16 + off] = loadx(z, gid, f32) * g_dinv[node];
    }
}

// ---- K6/K8: lane-per-(node,col4) sliced aggregation: 64 nodes x 1 slice per block ----
// lane = (node 0..15, col4 0..3): serial float4 gather per lane -> NO cross-lane
// reduce, b128 loads (16 rows/instr/wave), ~0.5 issue/edge.
// slice pinned via blockIdx&3 -> per-XCD 3.2MB table stays L2-resident.
template <int LAYER2>
__global__ __launch_bounds__(256) void aggslc_kernel(void* __restrict__ outp, int N) {
    __shared__ int rp[NPB + 1];
    __shared__ int eidx[ECAP];
    int s = blockIdx.x & (NSLC - 1);
    int n0 = (blockIdx.x >> 2) * NPB;
    int t = threadIdx.x;
    if (t <= NPB) {
        int idx = n0 + t;
        rp[t] = g_mrp[idx <= N ? idx : N];
    }
    __syncthreads();
    int base = rp[0];
    int range = rp[NPB] - base;
    bool staged = (range <= ECAP);
    if (staged) {
        for (int i = t; i < range; i += 256) eidx[i] = g_mcsr[base + i];
    }
    __syncthreads();
    const float* tab = (LAYER2 ? g_hs1 : g_agg1) + (size_t)s * ((size_t)N * 16);
    int lane = t & 63;
    int nsub = (t >> 6) * 16 + (lane >> 2);   // node index within block (0..63)
    int col4 = lane & 3;                      // float4 column (4 lanes per node)
    int nk = n0 + nsub;
    if (nk >= N) return;
    float4 a0 = make_float4(0.f, 0.f, 0.f, 0.f);
    float4 a1 = make_float4(0.f, 0.f, 0.f, 0.f);
    int jb = rp[nsub] - base;
    int je = rp[nsub + 1] - base;
    if (staged) {
        int j = jb;
        for (; j + 1 < je; j += 2) {
            int i0 = eidx[j], i1 = eidx[j + 1];
            float4 v0 = *(const float4*)&tab[(size_t)i0 * 16 + col4 * 4];
            float4 v1 = *(const float4*)&tab[(size_t)i1 * 16 + col4 * 4];
            a0.x += v0.x; a0.y += v0.y; a0.z += v0.z; a0.w += v0.w;
            a1.x += v1.x; a1.y += v1.y; a1.z += v1.z; a1.w += v1.w;
        }
        if (j < je) {
            float4 v0 = *(const float4*)&tab[(size_t)eidx[j] * 16 + col4 * 4];
            a0.x += v0.x; a0.y += v0.y; a0.z += v0.z; a0.w += v0.w;
        }
    } else {  // essentially-never fallback: direct global index walk
        for (int j = jb; j < je; j++) {
            float4 v0 = *(const float4*)&tab[(size_t)g_mcsr[base + j] * 16 + col4 * 4];
            a0.x += v0.x; a0.y += v0.y; a0.z += v0.z; a0.w += v0.w;
        }
    }
    float4 self = *(const float4*)&tab[(size_t)nk * 16 + col4 * 4];
    float dn = g_dinv[nk];
    float4 v;
    v.x = (a0.x + a1.x + self.x) * dn;
    v.y = (a0.y + a1.y + self.y) * dn;
    v.z = (a0.z + a1.z + self.z) * dn;
    v.w = (a0.w + a1.w + self.w) * dn;
    if (LAYER2) {
        float4 bias = *(const float4*)&g_b2f[s * 16 + col4 * 4];
        v.x += bias.x; v.y += bias.y; v.z += bias.z; v.w += bias.w;
        int oc = nk * 64 + s * 16 + col4 * 4;
        if (g_in_f32) {
            *(float4*)&((float*)outp)[oc] = v;
        } else {
            __hip_bfloat16* o = (__hip_bfloat16*)outp + oc;
            o[0] = __float2bfloat16(v.x);
            o[1] = __float2bfloat16(v.y);
            o[2] = __float2bfloat16(v.z);
            o[3] = __float2bfloat16(v.w);
        }
    } else {
        *(float4*)&g_hs1[(size_t)s * ((size_t)N * 16) + nk * 16 + col4 * 4] = v;
    }
}

// ---- K7: FUSED MLP per 64-row block: hs2 = (relu(aggz@W1+b1))@W2 * dinv ----
// 64 rows/block doubles FMA per W-load / LDS-load: gemm1 = 32 FMA/thread/k-iter,
// gemm2 = 64 FMA/thread/k4-iter -> latency chains covered by ILP.
// Single UNION LDS buffer [64][132] (33.8 KB): input (k<64) during gemm1, then h (k<128).
__global__ __launch_bounds__(256) void gemm_fused_kernel(int N) {
    __shared__ __align__(16) float B[64 * 132];   // 33792 B
    int t = threadIdx.x;
    int row0 = blockIdx.x * 64;
    // stage aggz (blocked [4][N][16]) row-major into B: 1024 float4 = 4/thread
#pragma unroll
    for (int s = 0; s < 4; s++) {
        int i = t + s * 256;
        int r = i >> 4, k4 = i & 15;
        int row = row0 + r;
        int g = k4 >> 2, off = (k4 & 3) * 4;
        float4 v = make_float4(0.f, 0.f, 0.f, 0.f);
        if (row < N) v = *(const float4*)&g_hs1[(size_t)g * (N * 16) + row * 16 + off];
        *(float4*)&B[r * 132 + k4 * 4] = v;
    }
    __syncthreads();
    // gemm1: 32 colgroups x 8 rowgroups, 8x4 micro-tile -> registers
    int cg1 = t & 31, rg1 = t >> 5;
    int c1 = cg1 * 4, r1 = rg1 * 8;
    float acc1[8][4] = {};
#pragma unroll 4
    for (int k = 0; k < IN_DIM; k++) {
        float b[4];
        *(float4*)b = *(const float4*)&g_W1f[k * HID_DIM + c1];
        float a[8];
#pragma unroll
        for (int i = 0; i < 8; i++) a[i] = B[(r1 + i) * 132 + k];
#pragma unroll
        for (int i = 0; i < 8; i++)
#pragma unroll
            for (int j = 0; j < 4; j++) acc1[i][j] = fmaf(a[i], b[j], acc1[i][j]);
    }
    __syncthreads();   // all input reads complete before h overwrites the buffer
    {
        float4 bias = *(const float4*)&g_b1f[c1];
#pragma unroll
        for (int i = 0; i < 8; i++) {
            float4 v;
            v.x = fmaxf(acc1[i][0] + bias.x, 0.f);
            v.y = fmaxf(acc1[i][1] + bias.y, 0.f);
            v.z = fmaxf(acc1[i][2] + bias.z, 0.f);
            v.w = fmaxf(acc1[i][3] + bias.w, 0.f);
            *(float4*)&B[(r1 + i) * 132 + c1] = v;
        }
    }
    __syncthreads();
    // gemm2: 16 colgroups x 16 rowgroups, 4x4 micro-tile; K=128 via float4 chunks of B
    {
        int cg = t & 15, rg = t >> 4;
        int c0 = cg * 4, r0 = rg * 4;
        float acc[4][4] = {};
#pragma unroll 2
        for (int k4 = 0; k4 < 32; k4++) {
            float av[4][4];
#pragma unroll
            for (int i = 0; i < 4; i++)
                *(float4*)av[i] = *(const float4*)&B[(r0 + i) * 132 + k4 * 4];
#pragma unroll
            for (int jj = 0; jj < 4; jj++) {
                float b[4];
                *(float4*)b = *(const float4*)&g_W2f[(k4 * 4 + jj) * OUT_DIM + c0];
#pragma unroll
                for (int i = 0; i < 4; i++)
#pragma unroll
                    for (int j = 0; j < 4; j++) acc[i][j] = fmaf(av[i][jj], b[j], acc[i][j]);
            }
        }
        int g = cg >> 2, off = (cg & 3) * 4;  // blocked output [4][N][16]
#pragma unroll
        for (int i = 0; i < 4; i++) {
            int row = row0 + r0 + i;
            if (row < N) {
                float dn = g_dinv[row];
                float4 v;
                v.x = acc[i][0] * dn;
                v.y = acc[i][1] * dn;
                v.z = acc[i][2] * dn;
                v.w = acc[i][3] * dn;
                *(float4*)&g_hs1[(size_t)g * (N * 16) + row * 16 + off] = v;
            }
        }
    }
}

extern "C" void kernel_launch(void* const* d_in, const int* in_sizes, int n_in,
                              void* d_out, int out_size, void* d_ws, size_t ws_size,
                              hipStream_t stream) {
    const void* z  = d_in[0];
    const void* ei = d_in[1];
    const void* W1 = d_in[2];
    const void* b1 = d_in[3];
    const void* W2 = d_in[4];
    const void* b2 = d_in[5];

    const int N = in_sizes[0] / IN_DIM;  // 50000
    const int E = in_sizes[1] / 2;       // 800000
    const int NE = NGRP * N;             // 400000
    const int NC8 = (NE + 255) / 256;    // 1563
    const int aggblocks = NSLC * ((N + NPB - 1) / NPB);  // 3128

    degprep_kernel<<<(E + 255) / 256, 256, 0, stream>>>(ei, (const unsigned short*)z, N, E);
    scans_kernel<<<NC8, 256, 0, stream>>>(N, NE);
    addoffs_kernel<<<NC8, 256, 0, stream>>>(N, NE, E);
    scatter_kernel<<<(E + 255) / 256, 256, 0, stream>>>(ei, N, E);
    mergezp_kernel<<<(N * 64 + 255) / 256, 256, 0, stream>>>(z, W1, b1, W2, b2, N);

    aggslc_kernel<0><<<aggblocks, 256, 0, stream>>>(d_out, N);
    gemm_fused_kernel<<<(N + 63) / 64, 256, 0, stream>>>(N);
    aggslc_kernel<1><<<aggblocks, 256, 0, stream>>>(d_out, N);
}